// Round 1
// baseline (909.525 us; speedup 1.0000x reference)
//
#include <hip/hip_runtime.h>
#include <cstdint>
#include <cstddef>

typedef _Float16 half8  __attribute__((ext_vector_type(8)));
typedef _Float16 half4v __attribute__((ext_vector_type(4)));
typedef float    f32x4  __attribute__((ext_vector_type(4)));

static constexpr int HWPX = 1024;
static constexpr int NPX  = 16384;
static constexpr int DBB  = 768;
static constexpr int DD   = 512;
static constexpr int KC   = 201;
static constexpr int KM   = 2010;   // KC * 10
static constexpr int KMP  = 2048;   // padded

// ---- workspace offsets (bytes) ----
static constexpr size_t OFF_MEAN  = 0;         // 768 f64
static constexpr size_t OFF_V     = 6144;      // 768 f64
static constexpr size_t OFF_VACC  = 12288;     // 768 f64
static constexpr size_t OFF_MM    = 18432;     // 2 f64
static constexpr size_t OFF_SQ    = 18688;     // 201 f64
static constexpr size_t OFF_ROW   = 20736;     // 2010 f64 (16080 B)
static constexpr size_t OFF_BK    = 36864;     // 201 i32
static constexpr size_t OFF_NCNT  = 37888;     // 2010 i32
static constexpr size_t OFF_GTSEG = 46080;     // 16384 i32
static constexpr size_t OFF_CORR  = 111616;    // 16384 i32
static constexpr size_t OFF_IDX   = 177152;    // 16384 i32
static constexpr size_t OFF_U     = 242688;    // 16384 f64
static constexpr size_t OFF_PN    = 373760;    // 2010*512 f32
static constexpr size_t OFF_P16   = 4490240;   // 2048*512 f16
static constexpr size_t OFF_C16   = 6587392;   // 16384*512 f16
static constexpr size_t OFF_QD    = 23364608;  // 16384*10 f32
static constexpr size_t OFF_W16   = 24019968;  // 512*768 f16
static constexpr size_t OFF_A16   = 24806400;  // 16384*768 f16 (dead after GEMM1)
static constexpr size_t OFF_OUTF  = 24806400;  // 16384*201 f32 (aliases A16, used after)
static constexpr size_t OFF_FPROTO= 37979136;  // 2010*512 f32 (aliases A16 tail; memset AFTER GEMM1)

// ---- d_out offsets (floats) ----
static constexpr size_t OUT_SEG = 0;
static constexpr size_t OUT_PL  = 3293184;
static constexpr size_t OUT_PT  = 36225024;
static constexpr size_t OUT_PG  = 36241408;
static constexpr size_t OUT_NP  = 36257792;

static __device__ __forceinline__ float  wredf(float x){
  #pragma unroll
  for (int o=32;o;o>>=1) x += __shfl_down(x,o);
  return x;
}
static __device__ __forceinline__ double wredd(double x){
  #pragma unroll
  for (int o=32;o;o>>=1) x += __shfl_down(x,o);
  return x;
}

// ================= PCA =================
__global__ __launch_bounds__(256) void kP0(const float* __restrict__ A, double* __restrict__ meanv){
  int lane = threadIdx.x & 63, w = threadIdx.x >> 6;
  int rbase = blockIdx.x*32 + w*8;
  double acc[12];
  #pragma unroll
  for (int j=0;j<12;j++) acc[j]=0.0;
  for (int i=0;i<8;i++){
    const float* Ar = A + (size_t)(rbase+i)*DBB;
    #pragma unroll
    for (int j=0;j<12;j++) acc[j] += (double)Ar[j*64+lane];
  }
  #pragma unroll
  for (int j=0;j<12;j++) atomicAdd(&meanv[j*64+lane], acc[j]);
}

__global__ void kInitV(double* __restrict__ meanv, double* __restrict__ v){
  int t = threadIdx.x;
  meanv[t] = meanv[t] * (1.0/16384.0);
  v[t] = 1.0/sqrt(768.0);
}

__global__ __launch_bounds__(256) void kPIter(const float* __restrict__ A, const double* __restrict__ meanv,
                                              const double* __restrict__ v, double* __restrict__ vacc){
  __shared__ double vs[768], ms[768];
  for (int t=threadIdx.x;t<768;t+=256){ vs[t]=v[t]; ms[t]=meanv[t]; }
  __syncthreads();
  int lane = threadIdx.x & 63, w = threadIdx.x >> 6;
  int rbase = blockIdx.x*32 + w*8;
  double acc[12];
  #pragma unroll
  for (int j=0;j<12;j++) acc[j]=0.0;
  for (int i=0;i<8;i++){
    const float* Ar = A + (size_t)(rbase+i)*DBB;
    double ad[12]; double wp = 0.0;
    #pragma unroll
    for (int j=0;j<12;j++){ int c=j*64+lane; ad[j] = (double)Ar[c]-ms[c]; wp += ad[j]*vs[c]; }
    wp = wredd(wp); wp = __shfl(wp, 0);
    #pragma unroll
    for (int j=0;j<12;j++) acc[j] += wp*ad[j];
  }
  #pragma unroll
  for (int j=0;j<12;j++) atomicAdd(&vacc[j*64+lane], acc[j]);
}

__global__ __launch_bounds__(256) void kPNorm(double* __restrict__ v, double* __restrict__ vacc){
  __shared__ double sp[4];
  __shared__ double snorm;
  int lane = threadIdx.x&63, w = threadIdx.x>>6;
  double s = 0.0;
  for (int d=threadIdx.x; d<768; d+=256){ double x=vacc[d]; s += x*x; }
  s = wredd(s);
  if (lane==0) sp[w]=s;
  __syncthreads();
  if (threadIdx.x==0) snorm = sqrt(sp[0]+sp[1]+sp[2]+sp[3]);
  __syncthreads();
  double nr = snorm;
  for (int d=threadIdx.x; d<768; d+=256){ v[d] = vacc[d]/nr; vacc[d]=0.0; }
}

__global__ __launch_bounds__(256) void kPU(const float* __restrict__ A, const double* __restrict__ meanv,
                                           const double* __restrict__ v, double* __restrict__ u){
  __shared__ double vs[768], ms[768];
  for (int t=threadIdx.x;t<768;t+=256){ vs[t]=v[t]; ms[t]=meanv[t]; }
  __syncthreads();
  int lane=threadIdx.x&63, w=threadIdx.x>>6;
  int rbase = blockIdx.x*32 + w*8;
  for (int i=0;i<8;i++){
    const float* Ar = A + (size_t)(rbase+i)*DBB;
    double wp=0.0;
    #pragma unroll
    for (int j=0;j<12;j++){ int c=j*64+lane; wp += ((double)Ar[c]-ms[c])*vs[c]; }
    wp = wredd(wp);
    if (lane==0) u[rbase+i] = wp;
  }
}

__global__ __launch_bounds__(1024) void kMinMax(const double* __restrict__ u, double* __restrict__ mm){
  __shared__ double smn[16], smx[16];
  int t = threadIdx.x;
  double mn = 1e300, mx = -1e300;
  for (int i=t;i<NPX;i+=1024){ double x=u[i]; mn = fmin(mn,x); mx = fmax(mx,x); }
  #pragma unroll
  for (int o=32;o;o>>=1){ mn = fmin(mn, __shfl_down(mn,o)); mx = fmax(mx, __shfl_down(mx,o)); }
  if ((t&63)==0){ smn[t>>6]=mn; smx[t>>6]=mx; }
  __syncthreads();
  if (t==0){
    for (int i=1;i<16;i++){ mn=fmin(mn,smn[i]); mx=fmax(mx,smx[i]); }
    mm[0]=mn; mm[1]=mx;
  }
}

__global__ __launch_bounds__(256) void kPseudo(const double* __restrict__ u, const double* __restrict__ mm,
      const int* __restrict__ gt, float* __restrict__ outPG, int* __restrict__ gtseg, int* __restrict__ Bk){
  int n = blockIdx.x*256 + threadIdx.x;
  int b = n >> 10;
  double us = (u[n]-mm[0])/(mm[1]-mm[0]);
  int c0 = gt[b];
  int g = (us < 0.5) ? c0 : 200;
  outPG[n] = (float)g;
  gtseg[n] = g;
  unsigned long long b0 = __ballot(g==c0);
  unsigned long long b1 = __ballot(g==200);
  if ((threadIdx.x&63)==0){
    atomicAdd(&Bk[c0], (int)__popcll(b0));
    atomicAdd(&Bk[200], (int)__popcll(b1));
  }
}

// ================= conversions / proto normalize =================
__global__ __launch_bounds__(256) void kConv(const float* __restrict__ src, _Float16* __restrict__ dst, int n4){
  int stride = gridDim.x*256;
  for (int i = blockIdx.x*256+threadIdx.x; i<n4; i+=stride){
    float4 vv = ((const float4*)src)[i];
    half4v h; h[0]=(_Float16)vv.x; h[1]=(_Float16)vv.y; h[2]=(_Float16)vv.z; h[3]=(_Float16)vv.w;
    ((half4v*)dst)[i] = h;
  }
}

__global__ __launch_bounds__(256) void kProtoNorm(const float* __restrict__ PR, float* __restrict__ Pn,
                                                  _Float16* __restrict__ P16){
  int w=threadIdx.x>>6, lane=threadIdx.x&63;
  int km = blockIdx.x*4 + w;
  if (km >= KMP) return;
  if (km >= KM){
    half8 z;
    #pragma unroll
    for (int i=0;i<8;i++) z[i]=(_Float16)0.0f;
    *(half8*)(P16 + (size_t)km*DD + lane*8) = z;
    return;
  }
  const float* r = PR + (size_t)km*DD + lane*8;
  float4 a = *(const float4*)r, b2 = *(const float4*)(r+4);
  float x[8] = {a.x,a.y,a.z,a.w,b2.x,b2.y,b2.z,b2.w};
  float ss=0;
  #pragma unroll
  for (int i=0;i<8;i++) ss += x[i]*x[i];
  ss = __shfl(wredf(ss),0);
  float nrm = fmaxf(sqrtf(ss), 1e-12f);
  float* pw = Pn + (size_t)km*DD + lane*8;
  half8 h;
  #pragma unroll
  for (int i=0;i<8;i++){ float vv = x[i]/nrm; pw[i]=vv; h[i]=(_Float16)vv; }
  *(half8*)(P16 + (size_t)km*DD + lane*8) = h;
}

// ================= fp16 MFMA GEMM (A[M,K] row-major, B[N,K] row-major = B^T form) =================
template<bool HALF_OUT>
__global__ __launch_bounds__(256) void gemm_f16(
    const _Float16* __restrict__ Am, const _Float16* __restrict__ Bm,
    float* __restrict__ Cf, _Float16* __restrict__ Ch,
    int Kd, int ldc, int ncols, const float* __restrict__ bias)
{
  __shared__ __align__(16) _Float16 As[128*40];
  __shared__ __align__(16) _Float16 Bs[128*40];
  const int tid = threadIdx.x;
  const int lane = tid & 63, w = tid >> 6;
  const int wr = w >> 1, wc = w & 1;
  const int lrow = lane & 15, kg = lane >> 4;
  const int m0 = blockIdx.x * 128, n0 = blockIdx.y * 128;
  const int srow = tid >> 2;
  const int scol = (tid & 3) * 8;

  f32x4 acc[4][4];
  #pragma unroll
  for (int i=0;i<4;i++)
    #pragma unroll
    for (int j=0;j<4;j++){ f32x4 z = {0.f,0.f,0.f,0.f}; acc[i][j]=z; }

  for (int k0 = 0; k0 < Kd; k0 += 32){
    #pragma unroll
    for (int i=0;i<2;i++){
      int r = i*64 + srow;
      *(int4*)(&As[r*40 + scol]) = *(const int4*)(Am + (size_t)(m0+r)*Kd + k0 + scol);
      *(int4*)(&Bs[r*40 + scol]) = *(const int4*)(Bm + (size_t)(n0+r)*Kd + k0 + scol);
    }
    __syncthreads();
    half8 af[4], bf[4];
    #pragma unroll
    for (int mi=0;mi<4;mi++) af[mi] = *(const half8*)(&As[(wr*64+mi*16+lrow)*40 + kg*8]);
    #pragma unroll
    for (int nj=0;nj<4;nj++) bf[nj] = *(const half8*)(&Bs[(wc*64+nj*16+lrow)*40 + kg*8]);
    #pragma unroll
    for (int mi=0;mi<4;mi++)
      #pragma unroll
      for (int nj=0;nj<4;nj++)
        acc[mi][nj] = __builtin_amdgcn_mfma_f32_16x16x32_f16(af[mi], bf[nj], acc[mi][nj], 0,0,0);
    __syncthreads();
  }
  #pragma unroll
  for (int mi=0;mi<4;mi++){
    int gr = m0 + wr*64 + mi*16 + kg*4;
    #pragma unroll
    for (int nj=0;nj<4;nj++){
      int gc = n0 + wc*64 + nj*16 + lrow;
      if (gc < ncols){
        float bv = bias ? bias[gc] : 0.0f;
        #pragma unroll
        for (int r2=0;r2<4;r2++){
          float vv = acc[mi][nj][r2] + bv;
          if (HALF_OUT) Ch[(size_t)(gr+r2)*ldc + gc] = (_Float16)vv;
          else          Cf[(size_t)(gr+r2)*ldc + gc] = vv;
        }
      }
    }
  }
}

// ================= LN + l2 normalize (in-place on C16) =================
__global__ __launch_bounds__(256) void kLNl2n(_Float16* __restrict__ C16,
      const float* __restrict__ fg, const float* __restrict__ fb){
  int w=threadIdx.x>>6, lane=threadIdx.x&63;
  int n = blockIdx.x*4 + w;
  _Float16* row = C16 + (size_t)n*DD + lane*8;
  half8 h = *(const half8*)row;
  float x[8];
  #pragma unroll
  for (int i=0;i<8;i++) x[i] = (float)h[i];
  float s=0;
  #pragma unroll
  for (int i=0;i<8;i++) s += x[i];
  float mu = __shfl(wredf(s),0)/512.f;
  float q=0;
  #pragma unroll
  for (int i=0;i<8;i++){ float d=x[i]-mu; q+=d*d; }
  float var = __shfl(wredf(q),0)/512.f;
  float inv = 1.f/sqrtf(var+1e-5f);
  float4 g0 = *(const float4*)(fg+lane*8), g1 = *(const float4*)(fg+lane*8+4);
  float4 b0 = *(const float4*)(fb+lane*8), b1 = *(const float4*)(fb+lane*8+4);
  float gg[8] = {g0.x,g0.y,g0.z,g0.w,g1.x,g1.y,g1.z,g1.w};
  float bb[8] = {b0.x,b0.y,b0.z,b0.w,b1.x,b1.y,b1.z,b1.w};
  float y[8]; float ss=0;
  #pragma unroll
  for (int i=0;i<8;i++){ y[i] = (x[i]-mu)*inv*gg[i]+bb[i]; ss += y[i]*y[i]; }
  float nrm = fmaxf(sqrtf(__shfl(wredf(ss),0)), 1e-12f);
  half8 o;
  #pragma unroll
  for (int i=0;i<8;i++) o[i] = (_Float16)(y[i]/nrm);
  *(half8*)row = o;
}

// ================= per-class max + mask LN + pred =================
__global__ __launch_bounds__(256) void kMaxLN(const float* __restrict__ PL, const float* __restrict__ mg,
    const float* __restrict__ mb, const int* __restrict__ gtseg,
    float* __restrict__ outf, int* __restrict__ corr){
  __shared__ float rowb[4][2016];
  int w=threadIdx.x>>6, lane=threadIdx.x&63;
  int n = blockIdx.x*4 + w;
  const float* src = PL + (size_t)n*KM;
  for (int j=lane;j<KM;j+=64) rowb[w][j] = src[j];
  __syncthreads();
  float xv[4]; int ncl=0;
  for (int c=lane;c<KC;c+=64){
    float mx = rowb[w][c*10];
    #pragma unroll
    for (int m=1;m<10;m++) mx = fmaxf(mx, rowb[w][c*10+m]);
    xv[ncl++] = mx;
  }
  float ps=0;
  for (int i=0;i<ncl;i++) ps += xv[i];
  float mu = __shfl(wredf(ps),0)/201.f;
  float pv=0;
  for (int i=0;i<ncl;i++){ float d=xv[i]-mu; pv+=d*d; }
  float var = __shfl(wredf(pv),0)/201.f;
  float inv = 1.f/sqrtf(var+1e-5f);
  float bv = -3.0e38f; int bi = 1<<30;
  for (int i=0;i<ncl;i++){
    int c = lane + i*64;
    float o = (xv[i]-mu)*inv*mg[c]+mb[c];
    outf[(size_t)n*KC + c] = o;
    if (o > bv){ bv=o; bi=c; }
  }
  #pragma unroll
  for (int o2=32;o2;o2>>=1){
    float ov = __shfl_down(bv,o2); int oi = __shfl_down(bi,o2);
    if (ov>bv || (ov==bv && oi<bi)){ bv=ov; bi=oi; }
  }
  if (lane==0) corr[n] = (bi==gtseg[n]) ? 1 : 0;
}

__global__ __launch_bounds__(256) void kTranspose(const float* __restrict__ of, float* __restrict__ outseg){
  __shared__ float tle[32][33];
  int b = blockIdx.z, k0 = blockIdx.y*32, hw0 = blockIdx.x*32;
  int j = threadIdx.x & 31, g = threadIdx.x >> 5;
  #pragma unroll
  for (int i=0;i<4;i++){
    int r = g*4+i;
    int k = k0 + j;
    tle[r][j] = (k<KC)? of[(size_t)(b*HWPX + hw0 + r)*KC + k] : 0.f;
  }
  __syncthreads();
  #pragma unroll
  for (int i=0;i<4;i++){
    int kl = g*4+i;
    int k = k0 + kl;
    if (k<KC) outseg[((size_t)b*KC + k)*HWPX + hw0 + j] = tle[j][kl];
  }
}

// ================= sinkhorn (dense [N,10] form) =================
__global__ __launch_bounds__(256) void kSKcos(const _Float16* __restrict__ C16, const _Float16* __restrict__ P16,
      const int* __restrict__ gtseg, float* __restrict__ Qd){
  int w=threadIdx.x>>6, lane=threadIdx.x&63;
  int n = blockIdx.x*4+w;
  int g = gtseg[n];
  half8 hc = *(const half8*)(C16 + (size_t)n*DD + lane*8);
  float c[8];
  #pragma unroll
  for (int i=0;i<8;i++) c[i]=(float)hc[i];
  const _Float16* Pb = P16 + (size_t)g*10*DD + lane*8;
  float qv[10];
  #pragma unroll
  for (int m=0;m<10;m++){
    half8 hp = *(const half8*)(Pb + m*DD);
    float d=0;
    #pragma unroll
    for (int i=0;i<8;i++) d += c[i]*(float)hp[i];
    qv[m] = wredf(d);
  }
  if (lane==0){
    #pragma unroll
    for (int m=0;m<10;m++) Qd[(size_t)n*10+m] = expf(qv[m]/0.05f);
  }
}

__global__ __launch_bounds__(256) void kSKsq(const float* __restrict__ Qd, const int* __restrict__ gtseg,
      const int* __restrict__ gt, double* __restrict__ sQ){
  __shared__ double part[4][2];
  int n = blockIdx.x*256 + threadIdx.x;
  int g = gtseg[n];
  int c0 = gt[blockIdx.x>>2];
  double s=0;
  #pragma unroll
  for (int m=0;m<10;m++) s += (double)Qd[(size_t)n*10+m];
  double p0 = (g==c0)? s:0.0, p1 = (g==200)? s:0.0;
  p0 = wredd(p0); p1 = wredd(p1);
  int w=threadIdx.x>>6, lane=threadIdx.x&63;
  if (lane==0){ part[w][0]=p0; part[w][1]=p1; }
  __syncthreads();
  if (threadIdx.x==0) atomicAdd(&sQ[c0], part[0][0]+part[1][0]+part[2][0]+part[3][0]);
  if (threadIdx.x==1) atomicAdd(&sQ[200], part[0][1]+part[1][1]+part[2][1]+part[3][1]);
}

__global__ __launch_bounds__(256) void kSKscale0(float* __restrict__ Qd, const int* __restrict__ gtseg,
      const double* __restrict__ sQ){
  int n = blockIdx.x*256+threadIdx.x;
  double s = sQ[gtseg[n]];
  if (s > 0.0){
    #pragma unroll
    for (int m=0;m<10;m++){
      size_t ix = (size_t)n*10+m;
      Qd[ix] = (float)((double)Qd[ix]/s);
    }
  }
}

__global__ __launch_bounds__(256) void kRow(const float* __restrict__ Qd, const int* __restrict__ gtseg,
     const int* __restrict__ gt, double* __restrict__ rowsum){
  __shared__ double part[4][10][2];
  int n = blockIdx.x*256+threadIdx.x;
  int g = gtseg[n];
  int c0 = gt[blockIdx.x>>2];
  int w=threadIdx.x>>6, lane=threadIdx.x&63;
  #pragma unroll
  for (int m=0;m<10;m++){
    double q = (double)Qd[(size_t)n*10+m];
    double p0 = (g==c0)? q:0.0;
    double p1 = (g==200)? q:0.0;
    p0=wredd(p0); p1=wredd(p1);
    if (lane==0){ part[w][m][0]=p0; part[w][m][1]=p1; }
  }
  __syncthreads();
  if (threadIdx.x < 20){
    int m = threadIdx.x>>1, cl = threadIdx.x&1;
    double t = part[0][m][cl]+part[1][m][cl]+part[2][m][cl]+part[3][m][cl];
    atomicAdd(&rowsum[m*KC + (cl?200:c0)], t);
  }
}

__global__ __launch_bounds__(256) void kColScale(float* __restrict__ Qd, const int* __restrict__ gtseg,
      const double* __restrict__ rowsum, const int* __restrict__ Bk){
  int n = blockIdx.x*256+threadIdx.x;
  int g = gtseg[n];
  int bk = Bk[g];
  double bsafe = (bk>0)? (double)bk : 1.0;
  double q[10]; double col=0.0;
  #pragma unroll
  for (int m=0;m<10;m++){
    double r = rowsum[m*KC+g];
    double t = (double)Qd[(size_t)n*10+m];
    if (r>0.0) t = t/r;
    t = t/10.0;
    q[m]=t; col+=t;
  }
  double cs = (col>0.0)? col : 1.0;
  #pragma unroll
  for (int m=0;m<10;m++) Qd[(size_t)n*10+m] = (float)(q[m]/cs/bsafe);
}

__global__ __launch_bounds__(256) void kSKfin(const float* __restrict__ Qd, const int* __restrict__ gtseg,
      const double* __restrict__ rowsum, int* __restrict__ idxp, float* __restrict__ outPT){
  int n = blockIdx.x*256+threadIdx.x;
  int g = gtseg[n];
  double bv = -1.0; int bi=0;
  #pragma unroll
  for (int m=0;m<10;m++){
    double r = rowsum[m*KC+g];
    double t = (double)Qd[(size_t)n*10+m];
    if (r>0.0) t=t/r;
    t=t/10.0;
    if (t>bv){ bv=t; bi=m; }
  }
  idxp[n]=bi;
  outPT[n]=(float)(bi + 10*g);
}

// ================= EMA prototype update =================
__global__ __launch_bounds__(256) void kEMAacc(const _Float16* __restrict__ C16, const int* __restrict__ gtseg,
     const int* __restrict__ corr, const int* __restrict__ idxp,
     float* __restrict__ fproto, int* __restrict__ ncnt){
  int w=threadIdx.x>>6, lane=threadIdx.x&63;
  int n = blockIdx.x*4+w;
  if (!corr[n]) return;
  int g = gtseg[n], m = idxp[n];
  half8 hc = *(const half8*)(C16 + (size_t)n*DD + lane*8);
  float* dst = fproto + ((size_t)g*10+m)*DD + lane*8;
  #pragma unroll
  for (int i=0;i<8;i++) atomicAdd(dst+i, (float)hc[i]);
  if (lane==0) atomicAdd(&ncnt[g*10+m], 1);
}

__global__ __launch_bounds__(256) void kEMAfin(const float* __restrict__ fproto, const int* __restrict__ ncnt,
     const float* __restrict__ Pn, float* __restrict__ outNP){
  int w=threadIdx.x>>6, lane=threadIdx.x&63;
  int km = blockIdx.x*4+w;
  if (km>=KM) return;
  const float* fr = fproto + (size_t)km*DD + lane*8;
  float fp[8]; float ss=0;
  #pragma unroll
  for (int i=0;i<8;i++){ fp[i]=fr[i]; ss+=fp[i]*fp[i]; }
  float n1 = fmaxf(sqrtf(__shfl(wredf(ss),0)), 1e-12f);
  int cnt = ncnt[km];
  const float* pr = Pn + (size_t)km*DD + lane*8;
  float t[8]; float s2=0;
  #pragma unroll
  for (int i=0;i<8;i++){
    float pv = pr[i];
    float tv = cnt ? (0.999f*pv + 0.001f*(fp[i]/n1)) : pv;
    t[i]=tv; s2+=tv*tv;
  }
  float n2 = fmaxf(sqrtf(__shfl(wredf(s2),0)), 1e-12f);
  float* dst = outNP + (size_t)km*DD + lane*8;
  #pragma unroll
  for (int i=0;i<8;i++) dst[i] = t[i]/n2;
}

// ================= launch =================
extern "C" void kernel_launch(void* const* d_in, const int* in_sizes, int n_in,
                              void* d_out, int out_size, void* d_ws, size_t ws_size,
                              hipStream_t stream) {
  const float* A   = (const float*)d_in[0];
  const int*   gt  = (const int*)d_in[1];
  const float* Wp  = (const float*)d_in[2];
  const float* pb  = (const float*)d_in[3];
  const float* fg  = (const float*)d_in[4];
  const float* fb  = (const float*)d_in[5];
  const float* mg  = (const float*)d_in[6];
  const float* mb  = (const float*)d_in[7];
  const float* PR  = (const float*)d_in[8];
  float* out = (float*)d_out;
  char* ws = (char*)d_ws;

  double* meanv  = (double*)(ws+OFF_MEAN);
  double* v      = (double*)(ws+OFF_V);
  double* vacc   = (double*)(ws+OFF_VACC);
  double* mm     = (double*)(ws+OFF_MM);
  double* sQ     = (double*)(ws+OFF_SQ);
  double* rowsum = (double*)(ws+OFF_ROW);
  int*    Bk     = (int*)(ws+OFF_BK);
  int*    ncnt   = (int*)(ws+OFF_NCNT);
  int*    gtseg  = (int*)(ws+OFF_GTSEG);
  int*    corr   = (int*)(ws+OFF_CORR);
  int*    idxp   = (int*)(ws+OFF_IDX);
  double* u      = (double*)(ws+OFF_U);
  float*  Pn     = (float*)(ws+OFF_PN);
  _Float16* P16  = (_Float16*)(ws+OFF_P16);
  _Float16* C16  = (_Float16*)(ws+OFF_C16);
  float*  Qd     = (float*)(ws+OFF_QD);
  _Float16* W16  = (_Float16*)(ws+OFF_W16);
  _Float16* A16  = (_Float16*)(ws+OFF_A16);
  float*  outf   = (float*)(ws+OFF_OUTF);
  float*  fproto = (float*)(ws+OFF_FPROTO);

  // zero small accumulators (mean/v/vacc/mm/sQ/rowsum/Bk/ncnt)
  hipMemsetAsync(ws, 0, 46080, stream);

  // ---- PCA pseudo-gt ----
  kP0<<<512,256,0,stream>>>(A, meanv);
  kInitV<<<1,768,0,stream>>>(meanv, v);
  for (int t=0;t<10;t++){
    kPIter<<<512,256,0,stream>>>(A, meanv, v, vacc);
    kPNorm<<<1,256,0,stream>>>(v, vacc);
  }
  kPU<<<512,256,0,stream>>>(A, meanv, v, u);
  kMinMax<<<1,1024,0,stream>>>(u, mm);
  kPseudo<<<64,256,0,stream>>>(u, mm, gt, out+OUT_PG, gtseg, Bk);

  // ---- convert + normalize protos ----
  kConv<<<2048,256,0,stream>>>(A, A16, NPX*DBB/4);
  kConv<<<384,256,0,stream>>>(Wp, W16, DD*DBB/4);
  kProtoNorm<<<512,256,0,stream>>>(PR, Pn, P16);

  // ---- GEMM1: f = A @ W^T + b  -> C16 (fp16) ----
  gemm_f16<true><<<dim3(128,4),256,0,stream>>>(A16, W16, nullptr, C16, DBB, DD, DD, pb);
  // fproto aliases A16's tail; A16 is dead now -> zero it here
  hipMemsetAsync(ws+OFF_FPROTO, 0, (size_t)KM*DD*4, stream);
  kLNl2n<<<4096,256,0,stream>>>(C16, fg, fb);

  // ---- GEMM2: proto_logits = _c @ protos^T ----
  gemm_f16<false><<<dim3(128,16),256,0,stream>>>(C16, P16, out+OUT_PL, nullptr, DD, KM, KM, nullptr);

  // ---- max over M + LN + pred; transpose to out_seg ----
  kMaxLN<<<4096,256,0,stream>>>(out+OUT_PL, mg, mb, gtseg, outf, corr);
  kTranspose<<<dim3(32,7,16),256,0,stream>>>(outf, out+OUT_SEG);

  // ---- sinkhorn ----
  kSKcos<<<4096,256,0,stream>>>(C16, P16, gtseg, Qd);
  kSKsq<<<64,256,0,stream>>>(Qd, gtseg, gt, sQ);
  kSKscale0<<<64,256,0,stream>>>(Qd, gtseg, sQ);
  for (int it=0; it<3; ++it){
    if (it) hipMemsetAsync(ws+OFF_ROW, 0, 16080, stream);
    kRow<<<64,256,0,stream>>>(Qd, gtseg, gt, rowsum);
    if (it<2) kColScale<<<64,256,0,stream>>>(Qd, gtseg, rowsum, Bk);
    else      kSKfin<<<64,256,0,stream>>>(Qd, gtseg, rowsum, idxp, out+OUT_PT);
  }

  // ---- EMA update ----
  kEMAacc<<<4096,256,0,stream>>>(C16, gtseg, corr, idxp, fproto, ncnt);
  kEMAfin<<<503,256,0,stream>>>(fproto, ncnt, Pn, out+OUT_NP);
}

// Round 2
// 861.818 us; speedup vs baseline: 1.0554x; 1.0554x over previous
//
#include <hip/hip_runtime.h>
#include <cstdint>
#include <cstddef>

typedef _Float16 half8  __attribute__((ext_vector_type(8)));
typedef _Float16 half4v __attribute__((ext_vector_type(4)));
typedef float    f32x4  __attribute__((ext_vector_type(4)));

static constexpr int HWPX = 1024;
static constexpr int NPX  = 16384;
static constexpr int DBB  = 768;
static constexpr int DD   = 512;
static constexpr int KC   = 201;
static constexpr int KM   = 2010;   // KC * 10
static constexpr int KMP  = 2048;   // padded

// ---- workspace offsets (bytes) ----
static constexpr size_t OFF_MEAN  = 0;         // 768 f64
static constexpr size_t OFF_ROW0  = 6144;      // 2016 f32
static constexpr size_t OFF_ROW3  = 14208;     // 2016 f32
static constexpr size_t OFF_ROW5  = 22272;     // 2016 f32
static constexpr size_t OFF_BK    = 30336;     // 201 i32
static constexpr size_t OFF_NCNT  = 31360;     // 2010 i32
static constexpr size_t OFF_MM    = 39552;     // 2 f64
static constexpr size_t ZSMALL    = 39808;     // memset1 range
static constexpr size_t OFF_GTSEG = 46080;     // 16384 i32
static constexpr size_t OFF_CORR  = 111616;    // 16384 i32
static constexpr size_t OFF_IDX   = 177152;    // 16384 i32
static constexpr size_t OFF_U     = 242688;    // 16384 f64
static constexpr size_t OFF_PN    = 373760;    // 2010*512 f32
static constexpr size_t OFF_P16   = 4490240;   // 2048*512 f16
static constexpr size_t OFF_C16   = 6587392;   // 16384*512 f16
static constexpr size_t OFF_QD    = 23364608;  // 16384*10 f32 ; first 67584 B alias the PCA x-chain (x0..x10)
static constexpr size_t OFF_W16   = 24019968;  // 512*768 f16
static constexpr size_t OFF_A16   = 24806400;  // 16384*768 f16 (dead after GEMM1)
static constexpr size_t OFF_OUTF  = 24806400;  // 16384*201 f32 (aliases A16, used after)
static constexpr size_t OFF_FPROTO= 37979136;  // 2010*512 f32 (aliases A16 tail; memset AFTER GEMM1)

// ---- d_out offsets (floats) ----
static constexpr size_t OUT_SEG = 0;
static constexpr size_t OUT_PL  = 3293184;
static constexpr size_t OUT_PT  = 36225024;
static constexpr size_t OUT_PG  = 36241408;
static constexpr size_t OUT_NP  = 36257792;

#define GLDS16(gp, lp) __builtin_amdgcn_global_load_lds( \
    (__attribute__((address_space(1))) const void*)(gp), \
    (__attribute__((address_space(3))) void*)(lp), 16, 0, 0)

static __device__ __forceinline__ float  wredf(float x){
  #pragma unroll
  for (int o=32;o;o>>=1) x += __shfl_down(x,o);
  return x;
}
static __device__ __forceinline__ double wredd(double x){
  #pragma unroll
  for (int o=32;o;o>>=1) x += __shfl_down(x,o);
  return x;
}

// ================= PCA =================
__global__ __launch_bounds__(256) void kP0(const float* __restrict__ A, double* __restrict__ meanv){
  int lane = threadIdx.x & 63, w = threadIdx.x >> 6;
  int rbase = blockIdx.x*32 + w*8;
  double acc[12];
  #pragma unroll
  for (int j=0;j<12;j++) acc[j]=0.0;
  for (int i=0;i<8;i++){
    const float* Ar = A + (size_t)(rbase+i)*DBB;
    #pragma unroll
    for (int j=0;j<12;j++) acc[j] += (double)Ar[j*64+lane];
  }
  #pragma unroll
  for (int j=0;j<12;j++) atomicAdd(&meanv[j*64+lane], acc[j]);
}

__global__ void kInitV(double* __restrict__ meanv, double* __restrict__ x0){
  int t = threadIdx.x;
  meanv[t] = meanv[t] * (1.0/16384.0);
  x0[t] = 1.0/sqrt(768.0);
}

// one un-normalized power-iteration step: y += Ac^T (Ac x)   (y pre-zeroed)
__global__ __launch_bounds__(256) void kPIter(const float* __restrict__ A, const double* __restrict__ meanv,
                                              const double* __restrict__ x, double* __restrict__ y){
  __shared__ double vs[768], ms[768];
  for (int t=threadIdx.x;t<768;t+=256){ vs[t]=x[t]; ms[t]=meanv[t]; }
  __syncthreads();
  int lane = threadIdx.x & 63, w = threadIdx.x >> 6;
  int rbase = blockIdx.x*32 + w*8;
  double acc[12];
  #pragma unroll
  for (int j=0;j<12;j++) acc[j]=0.0;
  for (int i=0;i<8;i++){
    const float* Ar = A + (size_t)(rbase+i)*DBB;
    double ad[12]; double wp = 0.0;
    #pragma unroll
    for (int j=0;j<12;j++){ int c=j*64+lane; ad[j] = (double)Ar[c]-ms[c]; wp += ad[j]*vs[c]; }
    wp = wredd(wp); wp = __shfl(wp, 0);
    #pragma unroll
    for (int j=0;j<12;j++) acc[j] += wp*ad[j];
  }
  #pragma unroll
  for (int j=0;j<12;j++) atomicAdd(&y[j*64+lane], acc[j]);
}

__global__ __launch_bounds__(256) void kPU(const float* __restrict__ A, const double* __restrict__ meanv,
                                           const double* __restrict__ v, double* __restrict__ u){
  __shared__ double vs[768], ms[768];
  for (int t=threadIdx.x;t<768;t+=256){ vs[t]=v[t]; ms[t]=meanv[t]; }
  __syncthreads();
  int lane=threadIdx.x&63, w=threadIdx.x>>6;
  int rbase = blockIdx.x*32 + w*8;
  for (int i=0;i<8;i++){
    const float* Ar = A + (size_t)(rbase+i)*DBB;
    double wp=0.0;
    #pragma unroll
    for (int j=0;j<12;j++){ int c=j*64+lane; wp += ((double)Ar[c]-ms[c])*vs[c]; }
    wp = wredd(wp);
    if (lane==0) u[rbase+i] = wp;
  }
}

__global__ __launch_bounds__(1024) void kMinMax(const double* __restrict__ u, double* __restrict__ mm){
  __shared__ double smn[16], smx[16];
  int t = threadIdx.x;
  double mn = 1e300, mx = -1e300;
  for (int i=t;i<NPX;i+=1024){ double x=u[i]; mn = fmin(mn,x); mx = fmax(mx,x); }
  #pragma unroll
  for (int o=32;o;o>>=1){ mn = fmin(mn, __shfl_down(mn,o)); mx = fmax(mx, __shfl_down(mx,o)); }
  if ((t&63)==0){ smn[t>>6]=mn; smx[t>>6]=mx; }
  __syncthreads();
  if (t==0){
    for (int i=1;i<16;i++){ mn=fmin(mn,smn[i]); mx=fmax(mx,smx[i]); }
    mm[0]=mn; mm[1]=mx;
  }
}

__global__ __launch_bounds__(256) void kPseudo(const double* __restrict__ u, const double* __restrict__ mm,
      const int* __restrict__ gt, float* __restrict__ outPG, int* __restrict__ gtseg, int* __restrict__ Bk){
  int n = blockIdx.x*256 + threadIdx.x;
  int b = n >> 10;
  double us = (u[n]-mm[0])/(mm[1]-mm[0]);
  int c0 = gt[b];
  int g = (us < 0.5) ? c0 : 200;
  outPG[n] = (float)g;
  gtseg[n] = g;
  unsigned long long b0 = __ballot(g==c0);
  unsigned long long b1 = __ballot(g==200);
  if ((threadIdx.x&63)==0){
    atomicAdd(&Bk[c0], (int)__popcll(b0));
    atomicAdd(&Bk[200], (int)__popcll(b1));
  }
}

// ================= conversions / proto normalize =================
__global__ __launch_bounds__(256) void kConv(const float* __restrict__ src, _Float16* __restrict__ dst, int n4){
  int stride = gridDim.x*256;
  for (int i = blockIdx.x*256+threadIdx.x; i<n4; i+=stride){
    float4 vv = ((const float4*)src)[i];
    half4v h; h[0]=(_Float16)vv.x; h[1]=(_Float16)vv.y; h[2]=(_Float16)vv.z; h[3]=(_Float16)vv.w;
    ((half4v*)dst)[i] = h;
  }
}

__global__ __launch_bounds__(256) void kProtoNorm(const float* __restrict__ PR, float* __restrict__ Pn,
                                                  _Float16* __restrict__ P16){
  int w=threadIdx.x>>6, lane=threadIdx.x&63;
  int km = blockIdx.x*4 + w;
  if (km >= KMP) return;
  if (km >= KM){
    half8 z;
    #pragma unroll
    for (int i=0;i<8;i++) z[i]=(_Float16)0.0f;
    *(half8*)(P16 + (size_t)km*DD + lane*8) = z;
    return;
  }
  const float* r = PR + (size_t)km*DD + lane*8;
  float4 a = *(const float4*)r, b2 = *(const float4*)(r+4);
  float x[8] = {a.x,a.y,a.z,a.w,b2.x,b2.y,b2.z,b2.w};
  float ss=0;
  #pragma unroll
  for (int i=0;i<8;i++) ss += x[i]*x[i];
  ss = __shfl(wredf(ss),0);
  float nrm = fmaxf(sqrtf(ss), 1e-12f);
  float* pw = Pn + (size_t)km*DD + lane*8;
  half8 h;
  #pragma unroll
  for (int i=0;i<8;i++){ float vv = x[i]/nrm; pw[i]=vv; h[i]=(_Float16)vv; }
  *(half8*)(P16 + (size_t)km*DD + lane*8) = h;
}

// ================= fp16 MFMA GEMM, BK=64, global_load_lds + XOR-swizzled LDS =================
// A[M,K] row-major, B[N,K] row-major (B^T form). LDS tile [128 rows][8 chunks of 16B],
// linear dest for global_load_lds; swizzle applied on the per-lane GLOBAL source
// (chunk csrc = c ^ (row&7)) and inverted on ds_read (T2 / m173 pattern, rule #21).
template<bool HALF_OUT>
__global__ __launch_bounds__(256) void gemm_f16(
    const _Float16* __restrict__ Am, const _Float16* __restrict__ Bm,
    float* __restrict__ Cf, _Float16* __restrict__ Ch,
    int Kd, int ldc, int ncols, const float* __restrict__ bias)
{
  __shared__ __align__(16) char As[128*128];
  __shared__ __align__(16) char Bs[128*128];
  const int tid = threadIdx.x;
  const int lane = tid & 63, w = tid >> 6;
  const int wr = w >> 1, wc = w & 1;
  const int lrow = lane & 15, kg = lane >> 4;
  const int m0 = blockIdx.x * 128, n0 = blockIdx.y * 128;

  f32x4 acc[4][4];
  #pragma unroll
  for (int i=0;i<4;i++)
    #pragma unroll
    for (int j=0;j<4;j++){ f32x4 z = {0.f,0.f,0.f,0.f}; acc[i][j]=z; }

  // precompute per-thread staging source geometry (same for all 4 issues modulo i)
  for (int k0 = 0; k0 < Kd; k0 += 64){
    #pragma unroll
    for (int i=0;i<4;i++){
      int slot = (i*4 + w)*64 + lane;      // 0..1023
      int r = slot >> 3;                   // 0..127
      int c = slot & 7;                    // 0..7
      int cs = c ^ (r & 7);                // swizzled source chunk
      GLDS16(Am + (size_t)(m0+r)*Kd + k0 + cs*8, As + (i*4+w)*1024);
      GLDS16(Bm + (size_t)(n0+r)*Kd + k0 + cs*8, Bs + (i*4+w)*1024);
    }
    __syncthreads();
    #pragma unroll
    for (int h=0; h<2; h++){
      half8 af[4], bf[4];
      #pragma unroll
      for (int mi=0;mi<4;mi++){
        int ar = wr*64 + mi*16 + lrow;
        af[mi] = *(const half8*)(As + ar*128 + (((h*4+kg) ^ (ar&7))<<4));
      }
      #pragma unroll
      for (int nj=0;nj<4;nj++){
        int br = wc*64 + nj*16 + lrow;
        bf[nj] = *(const half8*)(Bs + br*128 + (((h*4+kg) ^ (br&7))<<4));
      }
      #pragma unroll
      for (int mi=0;mi<4;mi++)
        #pragma unroll
        for (int nj=0;nj<4;nj++)
          acc[mi][nj] = __builtin_amdgcn_mfma_f32_16x16x32_f16(af[mi], bf[nj], acc[mi][nj], 0,0,0);
    }
    __syncthreads();
  }
  #pragma unroll
  for (int mi=0;mi<4;mi++){
    int gr = m0 + wr*64 + mi*16 + kg*4;
    #pragma unroll
    for (int nj=0;nj<4;nj++){
      int gc = n0 + wc*64 + nj*16 + lrow;
      if (gc < ncols){
        float bv = bias ? bias[gc] : 0.0f;
        #pragma unroll
        for (int r2=0;r2<4;r2++){
          float vv = acc[mi][nj][r2] + bv;
          if (HALF_OUT) Ch[(size_t)(gr+r2)*ldc + gc] = (_Float16)vv;
          else          Cf[(size_t)(gr+r2)*ldc + gc] = vv;
        }
      }
    }
  }
}

// ================= LN + l2 normalize (in-place on C16) =================
__global__ __launch_bounds__(256) void kLNl2n(_Float16* __restrict__ C16,
      const float* __restrict__ fg, const float* __restrict__ fb){
  int w=threadIdx.x>>6, lane=threadIdx.x&63;
  int n = blockIdx.x*4 + w;
  _Float16* row = C16 + (size_t)n*DD + lane*8;
  half8 h = *(const half8*)row;
  float x[8];
  #pragma unroll
  for (int i=0;i<8;i++) x[i] = (float)h[i];
  float s=0;
  #pragma unroll
  for (int i=0;i<8;i++) s += x[i];
  float mu = __shfl(wredf(s),0)/512.f;
  float q=0;
  #pragma unroll
  for (int i=0;i<8;i++){ float d=x[i]-mu; q+=d*d; }
  float var = __shfl(wredf(q),0)/512.f;
  float inv = 1.f/sqrtf(var+1e-5f);
  float4 g0 = *(const float4*)(fg+lane*8), g1 = *(const float4*)(fg+lane*8+4);
  float4 b0 = *(const float4*)(fb+lane*8), b1 = *(const float4*)(fb+lane*8+4);
  float gg[8] = {g0.x,g0.y,g0.z,g0.w,g1.x,g1.y,g1.z,g1.w};
  float bb[8] = {b0.x,b0.y,b0.z,b0.w,b1.x,b1.y,b1.z,b1.w};
  float y[8]; float ss=0;
  #pragma unroll
  for (int i=0;i<8;i++){ y[i] = (x[i]-mu)*inv*gg[i]+bb[i]; ss += y[i]*y[i]; }
  float nrm = fmaxf(sqrtf(__shfl(wredf(ss),0)), 1e-12f);
  half8 o;
  #pragma unroll
  for (int i=0;i<8;i++) o[i] = (_Float16)(y[i]/nrm);
  *(half8*)row = o;
}

// ================= per-class max + mask LN + pred =================
__global__ __launch_bounds__(256) void kMaxLN(const float* __restrict__ PL, const float* __restrict__ mg,
    const float* __restrict__ mb, const int* __restrict__ gtseg,
    float* __restrict__ outf, int* __restrict__ corr){
  __shared__ float rowb[4][2016];
  int w=threadIdx.x>>6, lane=threadIdx.x&63;
  int n = blockIdx.x*4 + w;
  const float* src = PL + (size_t)n*KM;
  for (int j=lane;j<KM;j+=64) rowb[w][j] = src[j];
  __syncthreads();
  float xv[4]; int ncl=0;
  for (int c=lane;c<KC;c+=64){
    float mx = rowb[w][c*10];
    #pragma unroll
    for (int m=1;m<10;m++) mx = fmaxf(mx, rowb[w][c*10+m]);
    xv[ncl++] = mx;
  }
  float ps=0;
  for (int i=0;i<ncl;i++) ps += xv[i];
  float mu = __shfl(wredf(ps),0)/201.f;
  float pv=0;
  for (int i=0;i<ncl;i++){ float d=xv[i]-mu; pv+=d*d; }
  float var = __shfl(wredf(pv),0)/201.f;
  float inv = 1.f/sqrtf(var+1e-5f);
  float bv = -3.0e38f; int bi = 1<<30;
  for (int i=0;i<ncl;i++){
    int c = lane + i*64;
    float o = (xv[i]-mu)*inv*mg[c]+mb[c];
    outf[(size_t)n*KC + c] = o;
    if (o > bv){ bv=o; bi=c; }
  }
  #pragma unroll
  for (int o2=32;o2;o2>>=1){
    float ov = __shfl_down(bv,o2); int oi = __shfl_down(bi,o2);
    if (ov>bv || (ov==bv && oi<bi)){ bv=ov; bi=oi; }
  }
  if (lane==0) corr[n] = (bi==gtseg[n]) ? 1 : 0;
}

__global__ __launch_bounds__(256) void kTranspose(const float* __restrict__ of, float* __restrict__ outseg){
  __shared__ float tle[32][33];
  int b = blockIdx.z, k0 = blockIdx.y*32, hw0 = blockIdx.x*32;
  int j = threadIdx.x & 31, g = threadIdx.x >> 5;
  #pragma unroll
  for (int i=0;i<4;i++){
    int r = g*4+i;
    int k = k0 + j;
    tle[r][j] = (k<KC)? of[(size_t)(b*HWPX + hw0 + r)*KC + k] : 0.f;
  }
  __syncthreads();
  #pragma unroll
  for (int i=0;i<4;i++){
    int kl = g*4+i;
    int k = k0 + kl;
    if (k<KC) outseg[((size_t)b*KC + k)*HWPX + hw0 + j] = tle[j][kl];
  }
}

// ================= sinkhorn (dense [N,10] form; sQ and final col/Bk scalings cancel) =================
__global__ __launch_bounds__(256) void kSKcos(const _Float16* __restrict__ C16, const _Float16* __restrict__ P16,
      const int* __restrict__ gtseg, float* __restrict__ Qd){
  int w=threadIdx.x>>6, lane=threadIdx.x&63;
  int n = blockIdx.x*4+w;
  int g = gtseg[n];
  half8 hc = *(const half8*)(C16 + (size_t)n*DD + lane*8);
  float c[8];
  #pragma unroll
  for (int i=0;i<8;i++) c[i]=(float)hc[i];
  const _Float16* Pb = P16 + (size_t)g*10*DD + lane*8;
  float qv[10];
  #pragma unroll
  for (int m=0;m<10;m++){
    half8 hp = *(const half8*)(Pb + m*DD);
    float d=0;
    #pragma unroll
    for (int i=0;i<8;i++) d += c[i]*(float)hp[i];
    qv[m] = wredf(d);
  }
  if (lane==0){
    #pragma unroll
    for (int m=0;m<10;m++) Qd[(size_t)n*10+m] = expf(qv[m]/0.05f);
  }
}

// row0[m,g] = sum_n Qd ; block covers one image -> exactly 2 classes
__global__ __launch_bounds__(256) void kRow0(const float* __restrict__ Qd, const int* __restrict__ gtseg,
     const int* __restrict__ gt, float* __restrict__ rout){
  __shared__ double part[4][10][2];
  int n = blockIdx.x*256+threadIdx.x;
  int g = gtseg[n];
  int c0 = gt[blockIdx.x>>2];
  int w=threadIdx.x>>6, lane=threadIdx.x&63;
  #pragma unroll
  for (int m=0;m<10;m++){
    double q = (double)Qd[(size_t)n*10+m];
    double p0 = (g==c0)? q:0.0;
    double p1 = (g==200)? q:0.0;
    p0=wredd(p0); p1=wredd(p1);
    if (lane==0){ part[w][m][0]=p0; part[w][m][1]=p1; }
  }
  __syncthreads();
  if (threadIdx.x < 20){
    int m = threadIdx.x>>1, cl = threadIdx.x&1;
    double t = part[0][m][cl]+part[1][m][cl]+part[2][m][cl]+part[3][m][cl];
    atomicAdd(&rout[m*KC + (cl?200:c0)], (float)t);
  }
}

// one sinkhorn iteration: Q = (Q/rin/M) ; col = sum_m ; Q = Q/col/Bk ; accumulate rout
__global__ __launch_bounds__(256) void kSKpass(float* __restrict__ Qd, const int* __restrict__ gtseg,
      const int* __restrict__ gt, const float* __restrict__ rin, float* __restrict__ rout,
      const int* __restrict__ Bk){
  __shared__ double part[4][10][2];
  int n = blockIdx.x*256+threadIdx.x;
  int g = gtseg[n];
  int c0 = gt[blockIdx.x>>2];
  double q[10]; double col=0.0;
  #pragma unroll
  for (int m=0;m<10;m++){
    double r = (double)rin[m*KC+g];
    double t = (double)Qd[(size_t)n*10+m];
    if (r>0.0) t = t/r;
    t = t/10.0;
    q[m]=t; col+=t;
  }
  double cs = (col>0.0)? col : 1.0;
  int bk = Bk[g];
  double bs = (bk>0)? (double)bk : 1.0;
  double inv = 1.0/(cs*bs);
  int w=threadIdx.x>>6, lane=threadIdx.x&63;
  #pragma unroll
  for (int m=0;m<10;m++){
    double t = q[m]*inv;
    Qd[(size_t)n*10+m] = (float)t;
    double p0 = (g==c0)? t:0.0;
    double p1 = (g==200)? t:0.0;
    p0=wredd(p0); p1=wredd(p1);
    if (lane==0){ part[w][m][0]=p0; part[w][m][1]=p1; }
  }
  __syncthreads();
  if (threadIdx.x < 20){
    int m = threadIdx.x>>1, cl = threadIdx.x&1;
    double t = part[0][m][cl]+part[1][m][cl]+part[2][m][cl]+part[3][m][cl];
    atomicAdd(&rout[m*KC + (cl?200:c0)], (float)t);
  }
}

// final: t = Q/row5/M ; argmax_m (col/Bk scaling is per-pixel positive -> argmax-invariant)
__global__ __launch_bounds__(256) void kSKfin(const float* __restrict__ Qd, const int* __restrict__ gtseg,
      const float* __restrict__ r5, int* __restrict__ idxp, float* __restrict__ outPT){
  int n = blockIdx.x*256+threadIdx.x;
  int g = gtseg[n];
  double bv = -1.0; int bi=0;
  #pragma unroll
  for (int m=0;m<10;m++){
    double r = (double)r5[m*KC+g];
    double t = (double)Qd[(size_t)n*10+m];
    if (r>0.0) t=t/r;
    t=t/10.0;
    if (t>bv){ bv=t; bi=m; }
  }
  idxp[n]=bi;
  outPT[n]=(float)(bi + 10*g);
}

// ================= EMA prototype update =================
__global__ __launch_bounds__(256) void kEMAacc(const _Float16* __restrict__ C16, const int* __restrict__ gtseg,
     const int* __restrict__ corr, const int* __restrict__ idxp,
     float* __restrict__ fproto, int* __restrict__ ncnt){
  int w=threadIdx.x>>6, lane=threadIdx.x&63;
  int n = blockIdx.x*4+w;
  if (!corr[n]) return;
  int g = gtseg[n], m = idxp[n];
  half8 hc = *(const half8*)(C16 + (size_t)n*DD + lane*8);
  float* dst = fproto + ((size_t)g*10+m)*DD + lane*8;
  #pragma unroll
  for (int i=0;i<8;i++) atomicAdd(dst+i, (float)hc[i]);
  if (lane==0) atomicAdd(&ncnt[g*10+m], 1);
}

__global__ __launch_bounds__(256) void kEMAfin(const float* __restrict__ fproto, const int* __restrict__ ncnt,
     const float* __restrict__ Pn, float* __restrict__ outNP){
  int w=threadIdx.x>>6, lane=threadIdx.x&63;
  int km = blockIdx.x*4+w;
  if (km>=KM) return;
  const float* fr = fproto + (size_t)km*DD + lane*8;
  float fp[8]; float ss=0;
  #pragma unroll
  for (int i=0;i<8;i++){ fp[i]=fr[i]; ss+=fp[i]*fp[i]; }
  float n1 = fmaxf(sqrtf(__shfl(wredf(ss),0)), 1e-12f);
  int cnt = ncnt[km];
  const float* pr = Pn + (size_t)km*DD + lane*8;
  float t[8]; float s2=0;
  #pragma unroll
  for (int i=0;i<8;i++){
    float pv = pr[i];
    float tv = cnt ? (0.999f*pv + 0.001f*(fp[i]/n1)) : pv;
    t[i]=tv; s2+=tv*tv;
  }
  float n2 = fmaxf(sqrtf(__shfl(wredf(s2),0)), 1e-12f);
  float* dst = outNP + (size_t)km*DD + lane*8;
  #pragma unroll
  for (int i=0;i<8;i++) dst[i] = t[i]/n2;
}

// ================= launch =================
extern "C" void kernel_launch(void* const* d_in, const int* in_sizes, int n_in,
                              void* d_out, int out_size, void* d_ws, size_t ws_size,
                              hipStream_t stream) {
  const float* A   = (const float*)d_in[0];
  const int*   gt  = (const int*)d_in[1];
  const float* Wp  = (const float*)d_in[2];
  const float* pb  = (const float*)d_in[3];
  const float* fg  = (const float*)d_in[4];
  const float* fb  = (const float*)d_in[5];
  const float* mg  = (const float*)d_in[6];
  const float* mb  = (const float*)d_in[7];
  const float* PR  = (const float*)d_in[8];
  float* out = (float*)d_out;
  char* ws = (char*)d_ws;

  double* meanv  = (double*)(ws+OFF_MEAN);
  float*  row0   = (float*)(ws+OFF_ROW0);
  float*  row3   = (float*)(ws+OFF_ROW3);
  float*  row5   = (float*)(ws+OFF_ROW5);
  int*    Bk     = (int*)(ws+OFF_BK);
  int*    ncnt   = (int*)(ws+OFF_NCNT);
  double* mm     = (double*)(ws+OFF_MM);
  int*    gtseg  = (int*)(ws+OFF_GTSEG);
  int*    corr   = (int*)(ws+OFF_CORR);
  int*    idxp   = (int*)(ws+OFF_IDX);
  double* u      = (double*)(ws+OFF_U);
  float*  Pn     = (float*)(ws+OFF_PN);
  _Float16* P16  = (_Float16*)(ws+OFF_P16);
  _Float16* C16  = (_Float16*)(ws+OFF_C16);
  float*  Qd     = (float*)(ws+OFF_QD);
  double* xchain = (double*)(ws+OFF_QD);   // x0..x10 alias Qd's head (Qd written later)
  _Float16* W16  = (_Float16*)(ws+OFF_W16);
  _Float16* A16  = (_Float16*)(ws+OFF_A16);
  float*  outf   = (float*)(ws+OFF_OUTF);
  float*  fproto = (float*)(ws+OFF_FPROTO);

  // zero small accumulators + PCA x-chain (x1..x10 are atomic destinations)
  hipMemsetAsync(ws, 0, ZSMALL, stream);
  hipMemsetAsync(ws+OFF_QD, 0, 11*768*8, stream);

  // ---- PCA pseudo-gt (un-normalized power iteration; direction-equivalent) ----
  kP0<<<512,256,0,stream>>>(A, meanv);
  kInitV<<<1,768,0,stream>>>(meanv, xchain);
  for (int t=0;t<10;t++){
    kPIter<<<512,256,0,stream>>>(A, meanv, xchain + t*768, xchain + (t+1)*768);
  }
  kPU<<<512,256,0,stream>>>(A, meanv, xchain + 10*768, u);
  kMinMax<<<1,1024,0,stream>>>(u, mm);
  kPseudo<<<64,256,0,stream>>>(u, mm, gt, out+OUT_PG, gtseg, Bk);

  // ---- convert + normalize protos ----
  kConv<<<2048,256,0,stream>>>(A, A16, NPX*DBB/4);
  kConv<<<384,256,0,stream>>>(Wp, W16, DD*DBB/4);
  kProtoNorm<<<512,256,0,stream>>>(PR, Pn, P16);

  // ---- GEMM1: f = A @ W^T + b  -> C16 (fp16) ----
  gemm_f16<true><<<dim3(128,4),256,0,stream>>>(A16, W16, nullptr, C16, DBB, DD, DD, pb);
  // fproto aliases A16's tail; A16 is dead now -> zero it here
  hipMemsetAsync(ws+OFF_FPROTO, 0, (size_t)KM*DD*4, stream);
  kLNl2n<<<4096,256,0,stream>>>(C16, fg, fb);

  // ---- GEMM2: proto_logits = _c @ protos^T ----
  gemm_f16<false><<<dim3(128,16),256,0,stream>>>(C16, P16, out+OUT_PL, nullptr, DD, KM, KM, nullptr);

  // ---- max over M + LN + pred; transpose to out_seg ----
  kMaxLN<<<4096,256,0,stream>>>(out+OUT_PL, mg, mb, gtseg, outf, corr);
  kTranspose<<<dim3(32,7,16),256,0,stream>>>(outf, out+OUT_SEG);

  // ---- sinkhorn (collapsed) ----
  kSKcos<<<4096,256,0,stream>>>(C16, P16, gtseg, Qd);
  kRow0<<<64,256,0,stream>>>(Qd, gtseg, gt, row0);
  kSKpass<<<64,256,0,stream>>>(Qd, gtseg, gt, row0, row3, Bk);
  kSKpass<<<64,256,0,stream>>>(Qd, gtseg, gt, row3, row5, Bk);
  kSKfin<<<64,256,0,stream>>>(Qd, gtseg, row5, idxp, out+OUT_PT);

  // ---- EMA update ----
  kEMAacc<<<4096,256,0,stream>>>(C16, gtseg, corr, idxp, fproto, ncnt);
  kEMAfin<<<503,256,0,stream>>>(fproto, ncnt, Pn, out+OUT_NP);
}

// Round 3
// 406.160 us; speedup vs baseline: 2.2393x; 2.1219x over previous
//
#include <hip/hip_runtime.h>
#include <cstdint>
#include <cstddef>

typedef _Float16 half8  __attribute__((ext_vector_type(8)));
typedef _Float16 half4v __attribute__((ext_vector_type(4)));
typedef float    f32x4  __attribute__((ext_vector_type(4)));

static constexpr int HWPX = 1024;
static constexpr int NPX  = 16384;
static constexpr int DBB  = 768;
static constexpr int DD   = 512;
static constexpr int KC   = 201;
static constexpr int KM   = 2010;   // KC * 10
static constexpr int KMP  = 2048;   // padded

// ---- workspace offsets (bytes); ws_size ~596 MB (observed poison fill) ----
static constexpr size_t OFF_MEANP  = 0;        // [8][768] f64 partials = 49152
static constexpr size_t OFF_XCH    = 49152;    // [10][8][768] f64 iterate partials = 491520
static constexpr size_t OFF_ROW16  = 540672;   // [16][2016] f32 = 129024
static constexpr size_t OFF_ROW3   = 669696;   // [2016] f32
static constexpr size_t OFF_ROW5   = 677760;   // [2016] f32
static constexpr size_t OFF_BK     = 685824;   // 256 i32
static constexpr size_t OFF_NCNT   = 686848;   // 2016 i32
static constexpr size_t OFF_MM     = 694912;   // 2 f64
static constexpr size_t OFF_FPROTO = 695296;   // 2010*512 f32 = 4116480
static constexpr size_t ZTOTAL     = 4811776;  // one memset covers all of the above
static constexpr size_t OFF_GTSEG  = 4849664;  // 16384 i32
static constexpr size_t OFF_CORR   = 4915200;  // 16384 i32
static constexpr size_t OFF_U      = 4980736;  // 16384 f64
static constexpr size_t OFF_PN     = 5111808;  // 2010*512 f32
static constexpr size_t OFF_P16    = 9228288;  // 2048*512 f16
static constexpr size_t OFF_C16    = 11325440; // 16384*512 f16
static constexpr size_t OFF_QD     = 28102656; // 16384*10 f32
static constexpr size_t OFF_W16    = 28758016; // 512*768 f16
static constexpr size_t OFF_A16    = 29544448; // 16384*768 f16  (end ~54.7 MB)

// ---- d_out offsets (floats) ----
static constexpr size_t OUT_SEG = 0;
static constexpr size_t OUT_PL  = 3293184;
static constexpr size_t OUT_PT  = 36225024;
static constexpr size_t OUT_PG  = 36241408;
static constexpr size_t OUT_NP  = 36257792;

#define GLDS16(gp, lp) __builtin_amdgcn_global_load_lds( \
    (__attribute__((address_space(1))) const void*)(gp), \
    (__attribute__((address_space(3))) void*)(lp), 16, 0, 0)

static __device__ __forceinline__ float  wredf(float x){
  #pragma unroll
  for (int o=32;o;o>>=1) x += __shfl_down(x,o);
  return x;
}
static __device__ __forceinline__ double wredd(double x){
  #pragma unroll
  for (int o=32;o;o>>=1) x += __shfl_down(x,o);
  return x;
}

// ================= PCA =================
// Column sums of A -> meanp partials (8 buffers). 1024 blocks, 16 rows/block (4/wave).
__global__ __launch_bounds__(256) void kP0(const float* __restrict__ A, double* __restrict__ meanp){
  __shared__ double red[4][12][64];
  int lane = threadIdx.x & 63, w = threadIdx.x >> 6;
  int rbase = blockIdx.x*16 + w*4;
  double acc[12];
  #pragma unroll
  for (int j=0;j<12;j++) acc[j]=0.0;
  for (int i=0;i<4;i++){
    const float* Ar = A + (size_t)(rbase+i)*DBB;
    #pragma unroll
    for (int j=0;j<12;j++) acc[j] += (double)Ar[j*64+lane];
  }
  #pragma unroll
  for (int j=0;j<12;j++) red[w][j][lane] = acc[j];
  __syncthreads();
  double* dst = meanp + (size_t)(blockIdx.x&7)*768;
  for (int cc=threadIdx.x; cc<768; cc+=256){
    int j = cc>>6, l = cc&63;
    double s = red[0][j][l]+red[1][j][l]+red[2][j][l]+red[3][j][l];
    atomicAdd(&dst[cc], s);
  }
}

// one un-normalized power-iteration step: y_partials += Ac^T (Ac x)
// xp==nullptr -> x = const 1/sqrt(768)
__global__ __launch_bounds__(256) void kPIter(const float* __restrict__ A, const double* __restrict__ meanp,
                                              const double* __restrict__ xp, double* __restrict__ y){
  __shared__ double vs[768], ms[768];
  __shared__ double red[4][12][64];
  for (int cc=threadIdx.x; cc<768; cc+=256){
    double sm=0.0;
    #pragma unroll
    for (int p=0;p<8;p++) sm += meanp[p*768+cc];
    ms[cc] = sm * (1.0/16384.0);
    if (xp){
      double sv=0.0;
      #pragma unroll
      for (int p=0;p<8;p++) sv += xp[p*768+cc];
      vs[cc] = sv;
    } else {
      vs[cc] = 1.0/sqrt(768.0);
    }
  }
  __syncthreads();
  int lane = threadIdx.x & 63, w = threadIdx.x >> 6;
  int rbase = blockIdx.x*16 + w*4;
  double acc[12];
  #pragma unroll
  for (int j=0;j<12;j++) acc[j]=0.0;
  for (int i=0;i<4;i++){
    const float* Ar = A + (size_t)(rbase+i)*DBB;
    double ad[12]; double wp = 0.0;
    #pragma unroll
    for (int j=0;j<12;j++){ int c=j*64+lane; ad[j] = (double)Ar[c]-ms[c]; wp += ad[j]*vs[c]; }
    wp = wredd(wp); wp = __shfl(wp, 0);
    #pragma unroll
    for (int j=0;j<12;j++) acc[j] += wp*ad[j];
  }
  #pragma unroll
  for (int j=0;j<12;j++) red[w][j][lane] = acc[j];
  __syncthreads();
  double* dst = y + (size_t)(blockIdx.x&7)*768;
  for (int cc=threadIdx.x; cc<768; cc+=256){
    int j = cc>>6, l = cc&63;
    double s = red[0][j][l]+red[1][j][l]+red[2][j][l]+red[3][j][l];
    atomicAdd(&dst[cc], s);
  }
}

// u = Ac v   (v from 8 partials)
__global__ __launch_bounds__(256) void kPU(const float* __restrict__ A, const double* __restrict__ meanp,
                                           const double* __restrict__ vp, double* __restrict__ u){
  __shared__ double vs[768], ms[768];
  for (int cc=threadIdx.x; cc<768; cc+=256){
    double sm=0.0, sv=0.0;
    #pragma unroll
    for (int p=0;p<8;p++){ sm += meanp[p*768+cc]; sv += vp[p*768+cc]; }
    ms[cc] = sm * (1.0/16384.0);
    vs[cc] = sv;
  }
  __syncthreads();
  int lane=threadIdx.x&63, w=threadIdx.x>>6;
  int rbase = blockIdx.x*16 + w*4;
  for (int i=0;i<4;i++){
    const float* Ar = A + (size_t)(rbase+i)*DBB;
    double wp=0.0;
    #pragma unroll
    for (int j=0;j<12;j++){ int c=j*64+lane; wp += ((double)Ar[c]-ms[c])*vs[c]; }
    wp = wredd(wp);
    if (lane==0) u[rbase+i] = wp;
  }
}

__global__ __launch_bounds__(1024) void kMinMax(const double* __restrict__ u, double* __restrict__ mm){
  __shared__ double smn[16], smx[16];
  int t = threadIdx.x;
  double mn = 1e300, mx = -1e300;
  for (int i=t;i<NPX;i+=1024){ double x=u[i]; mn = fmin(mn,x); mx = fmax(mx,x); }
  #pragma unroll
  for (int o=32;o;o>>=1){ mn = fmin(mn, __shfl_down(mn,o)); mx = fmax(mx, __shfl_down(mx,o)); }
  if ((t&63)==0){ smn[t>>6]=mn; smx[t>>6]=mx; }
  __syncthreads();
  if (t==0){
    for (int i=1;i<16;i++){ mn=fmin(mn,smn[i]); mx=fmax(mx,smx[i]); }
    mm[0]=mn; mm[1]=mx;
  }
}

__global__ __launch_bounds__(256) void kPseudo(const double* __restrict__ u, const double* __restrict__ mm,
      const int* __restrict__ gt, float* __restrict__ outPG, int* __restrict__ gtseg, int* __restrict__ Bk){
  int n = blockIdx.x*256 + threadIdx.x;
  int b = n >> 10;
  double us = (u[n]-mm[0])/(mm[1]-mm[0]);
  int c0 = gt[b];
  int g = (us < 0.5) ? c0 : 200;
  outPG[n] = (float)g;
  gtseg[n] = g;
  unsigned long long b0 = __ballot(g==c0);
  unsigned long long b1 = __ballot(g==200);
  if ((threadIdx.x&63)==0){
    atomicAdd(&Bk[c0], (int)__popcll(b0));
    atomicAdd(&Bk[200], (int)__popcll(b1));
  }
}

// ================= conversions / proto normalize =================
__global__ __launch_bounds__(256) void kConv(const float* __restrict__ src, _Float16* __restrict__ dst, int n4){
  int stride = gridDim.x*256;
  for (int i = blockIdx.x*256+threadIdx.x; i<n4; i+=stride){
    float4 vv = ((const float4*)src)[i];
    half4v h; h[0]=(_Float16)vv.x; h[1]=(_Float16)vv.y; h[2]=(_Float16)vv.z; h[3]=(_Float16)vv.w;
    ((half4v*)dst)[i] = h;
  }
}

__global__ __launch_bounds__(256) void kProtoNorm(const float* __restrict__ PR, float* __restrict__ Pn,
                                                  _Float16* __restrict__ P16){
  int w=threadIdx.x>>6, lane=threadIdx.x&63;
  int km = blockIdx.x*4 + w;
  if (km >= KMP) return;
  if (km >= KM){
    half8 z;
    #pragma unroll
    for (int i=0;i<8;i++) z[i]=(_Float16)0.0f;
    *(half8*)(P16 + (size_t)km*DD + lane*8) = z;
    return;
  }
  const float* r = PR + (size_t)km*DD + lane*8;
  float4 a = *(const float4*)r, b2 = *(const float4*)(r+4);
  float x[8] = {a.x,a.y,a.z,a.w,b2.x,b2.y,b2.z,b2.w};
  float ss=0;
  #pragma unroll
  for (int i=0;i<8;i++) ss += x[i]*x[i];
  ss = __shfl(wredf(ss),0);
  float nrm = fmaxf(sqrtf(ss), 1e-12f);
  float* pw = Pn + (size_t)km*DD + lane*8;
  half8 h;
  #pragma unroll
  for (int i=0;i<8;i++){ float vv = x[i]/nrm; pw[i]=vv; h[i]=(_Float16)vv; }
  *(half8*)(P16 + (size_t)km*DD + lane*8) = h;
}

// ================= fp16 MFMA GEMM, BK=64, global_load_lds + XOR-swizzled LDS =================
template<bool HALF_OUT>
__global__ __launch_bounds__(256) void gemm_f16(
    const _Float16* __restrict__ Am, const _Float16* __restrict__ Bm,
    float* __restrict__ Cf, _Float16* __restrict__ Ch,
    int Kd, int ldc, int ncols, const float* __restrict__ bias)
{
  __shared__ __align__(16) char As[128*128];
  __shared__ __align__(16) char Bs[128*128];
  const int tid = threadIdx.x;
  const int lane = tid & 63, w = tid >> 6;
  const int wr = w >> 1, wc = w & 1;
  const int lrow = lane & 15, kg = lane >> 4;
  const int m0 = blockIdx.x * 128, n0 = blockIdx.y * 128;

  f32x4 acc[4][4];
  #pragma unroll
  for (int i=0;i<4;i++)
    #pragma unroll
    for (int j=0;j<4;j++){ f32x4 z = {0.f,0.f,0.f,0.f}; acc[i][j]=z; }

  for (int k0 = 0; k0 < Kd; k0 += 64){
    #pragma unroll
    for (int i=0;i<4;i++){
      int slot = (i*4 + w)*64 + lane;      // 0..1023
      int r = slot >> 3;                   // 0..127
      int c = slot & 7;                    // 0..7
      int cs = c ^ (r & 7);                // swizzled source chunk
      GLDS16(Am + (size_t)(m0+r)*Kd + k0 + cs*8, As + (i*4+w)*1024);
      GLDS16(Bm + (size_t)(n0+r)*Kd + k0 + cs*8, Bs + (i*4+w)*1024);
    }
    __syncthreads();
    #pragma unroll
    for (int h=0; h<2; h++){
      half8 af[4], bf[4];
      #pragma unroll
      for (int mi=0;mi<4;mi++){
        int ar = wr*64 + mi*16 + lrow;
        af[mi] = *(const half8*)(As + ar*128 + (((h*4+kg) ^ (ar&7))<<4));
      }
      #pragma unroll
      for (int nj=0;nj<4;nj++){
        int br = wc*64 + nj*16 + lrow;
        bf[nj] = *(const half8*)(Bs + br*128 + (((h*4+kg) ^ (br&7))<<4));
      }
      #pragma unroll
      for (int mi=0;mi<4;mi++)
        #pragma unroll
        for (int nj=0;nj<4;nj++)
          acc[mi][nj] = __builtin_amdgcn_mfma_f32_16x16x32_f16(af[mi], bf[nj], acc[mi][nj], 0,0,0);
    }
    __syncthreads();
  }
  #pragma unroll
  for (int mi=0;mi<4;mi++){
    int gr = m0 + wr*64 + mi*16 + kg*4;
    #pragma unroll
    for (int nj=0;nj<4;nj++){
      int gc = n0 + wc*64 + nj*16 + lrow;
      if (gc < ncols){
        float bv = bias ? bias[gc] : 0.0f;
        #pragma unroll
        for (int r2=0;r2<4;r2++){
          float vv = acc[mi][nj][r2] + bv;
          if (HALF_OUT) Ch[(size_t)(gr+r2)*ldc + gc] = (_Float16)vv;
          else          Cf[(size_t)(gr+r2)*ldc + gc] = vv;
        }
      }
    }
  }
}

// ================= LN + l2 normalize (in-place on C16) =================
__global__ __launch_bounds__(256) void kLNl2n(_Float16* __restrict__ C16,
      const float* __restrict__ fg, const float* __restrict__ fb){
  int w=threadIdx.x>>6, lane=threadIdx.x&63;
  int n = blockIdx.x*4 + w;
  _Float16* row = C16 + (size_t)n*DD + lane*8;
  half8 h = *(const half8*)row;
  float x[8];
  #pragma unroll
  for (int i=0;i<8;i++) x[i] = (float)h[i];
  float s=0;
  #pragma unroll
  for (int i=0;i<8;i++) s += x[i];
  float mu = __shfl(wredf(s),0)/512.f;
  float q=0;
  #pragma unroll
  for (int i=0;i<8;i++){ float d=x[i]-mu; q+=d*d; }
  float var = __shfl(wredf(q),0)/512.f;
  float inv = 1.f/sqrtf(var+1e-5f);
  float4 g0 = *(const float4*)(fg+lane*8), g1 = *(const float4*)(fg+lane*8+4);
  float4 b0 = *(const float4*)(fb+lane*8), b1 = *(const float4*)(fb+lane*8+4);
  float gg[8] = {g0.x,g0.y,g0.z,g0.w,g1.x,g1.y,g1.z,g1.w};
  float bb[8] = {b0.x,b0.y,b0.z,b0.w,b1.x,b1.y,b1.z,b1.w};
  float y[8]; float ss=0;
  #pragma unroll
  for (int i=0;i<8;i++){ y[i] = (x[i]-mu)*inv*gg[i]+bb[i]; ss += y[i]*y[i]; }
  float nrm = fmaxf(sqrtf(__shfl(wredf(ss),0)), 1e-12f);
  half8 o;
  #pragma unroll
  for (int i=0;i<8;i++) o[i] = (_Float16)(y[i]/nrm);
  *(half8*)row = o;
}

// ================= fused per-class max + mask LN + pred + transpose-out =================
__global__ __launch_bounds__(256) void kMaxLNT(const float* __restrict__ PL, const float* __restrict__ mg,
    const float* __restrict__ mb, const int* __restrict__ gtseg,
    float* __restrict__ outseg, int* __restrict__ corr){
  __shared__ float rowb[4][2016];
  __shared__ float tile[32][205];
  int w=threadIdx.x>>6, lane=threadIdx.x&63;
  int n0 = blockIdx.x*32;
  int b = n0>>10, hw0 = n0&1023;
  for (int g8=0; g8<8; ++g8){
    int n = n0 + g8*4 + w;
    const float* src = PL + (size_t)n*KM;
    for (int j=lane;j<KM;j+=64) rowb[w][j] = src[j];
    // wave-local staging: no cross-wave sharing, no barrier needed
    float xv[4]; int ncl=0;
    for (int c=lane;c<KC;c+=64){
      float mx = rowb[w][c*10];
      #pragma unroll
      for (int m=1;m<10;m++) mx = fmaxf(mx, rowb[w][c*10+m]);
      xv[ncl++] = mx;
    }
    float ps=0;
    for (int i=0;i<ncl;i++) ps += xv[i];
    float mu = __shfl(wredf(ps),0)*(1.f/201.f);
    float pv=0;
    for (int i=0;i<ncl;i++){ float d=xv[i]-mu; pv+=d*d; }
    float var = __shfl(wredf(pv),0)*(1.f/201.f);
    float inv = 1.f/sqrtf(var+1e-5f);
    float bv = -3.0e38f; int bi = 1<<30;
    int lr = g8*4 + w;
    ncl = 0;
    for (int c=lane;c<KC;c+=64){
      float o = (xv[ncl]-mu)*inv*mg[c]+mb[c]; ncl++;
      tile[lr][c] = o;
      if (o > bv){ bv=o; bi=c; }
    }
    #pragma unroll
    for (int o2=32;o2;o2>>=1){
      float ov = __shfl_down(bv,o2); int oi = __shfl_down(bi,o2);
      if (ov>bv || (ov==bv && oi<bi)){ bv=ov; bi=oi; }
    }
    if (lane==0) corr[n] = (bi==gtseg[n]) ? 1 : 0;
  }
  __syncthreads();
  for (int idx=threadIdx.x; idx<KC*32; idx+=256){
    int c = idx>>5, j = idx&31;
    outseg[(((size_t)b*KC+c)<<10) + hw0 + j] = tile[j][c];
  }
}

// ================= sinkhorn (dense [N,10]; sQ and final col/Bk scalings cancel) =================
// fused: cosine+exp -> Qd ; block-reduced row-sums into 16 partial buffers
__global__ __launch_bounds__(256) void kSKcosRow(const _Float16* __restrict__ C16, const _Float16* __restrict__ P16,
      const int* __restrict__ gtseg, const int* __restrict__ gt,
      float* __restrict__ Qd, float* __restrict__ row16){
  __shared__ double part[4][10][2];
  int w=threadIdx.x>>6, lane=threadIdx.x&63;
  int n = blockIdx.x*4+w;
  int g = gtseg[n];
  int c0 = gt[n>>10];
  half8 hc = *(const half8*)(C16 + (size_t)n*DD + lane*8);
  float c[8];
  #pragma unroll
  for (int i=0;i<8;i++) c[i]=(float)hc[i];
  const _Float16* Pb = P16 + (size_t)g*10*DD + lane*8;
  #pragma unroll
  for (int m=0;m<10;m++){
    half8 hp = *(const half8*)(Pb + m*DD);
    float d=0;
    #pragma unroll
    for (int i=0;i<8;i++) d += c[i]*(float)hp[i];
    float qv = wredf(d);
    if (lane==0){
      float e = expf(qv*20.f);
      Qd[(size_t)n*10+m] = e;
      part[w][m][0] = (g==c0)? (double)e : 0.0;
      part[w][m][1] = (g==200)? (double)e : 0.0;
    }
  }
  __syncthreads();
  if (threadIdx.x < 20){
    int m = threadIdx.x>>1, cl = threadIdx.x&1;
    double t = part[0][m][cl]+part[1][m][cl]+part[2][m][cl]+part[3][m][cl];
    atomicAdd(&row16[(size_t)(blockIdx.x&15)*2016 + m*KC + (cl?200:c0)], (float)t);
  }
}

// one sinkhorn iteration; rin has rin_parts partial buffers of stride 2016
__global__ __launch_bounds__(256) void kSKpass(float* __restrict__ Qd, const int* __restrict__ gtseg,
      const int* __restrict__ gt, const float* __restrict__ rin, int rin_parts,
      float* __restrict__ rout, const int* __restrict__ Bk){
  __shared__ float rin2[10][2];
  __shared__ double part[4][10][2];
  int n = blockIdx.x*256+threadIdx.x;
  int c0 = gt[blockIdx.x>>2];
  if (threadIdx.x < 20){
    int m = threadIdx.x>>1, cl = threadIdx.x&1;
    int cls = cl?200:c0;
    float s=0;
    for (int p=0;p<rin_parts;p++) s += rin[(size_t)p*2016 + m*KC + cls];
    rin2[m][cl]=s;
  }
  __syncthreads();
  int g = gtseg[n];
  int cl = (g==200)?1:0;
  double q[10]; double col=0.0;
  #pragma unroll
  for (int m=0;m<10;m++){
    double r = (double)rin2[m][cl];
    double t = (double)Qd[(size_t)n*10+m];
    if (r>0.0) t = t/r;
    t = t/10.0;
    q[m]=t; col+=t;
  }
  double cs = (col>0.0)? col : 1.0;
  int bk = Bk[g];
  double bs = (bk>0)? (double)bk : 1.0;
  double inv = 1.0/(cs*bs);
  int w=threadIdx.x>>6, lane=threadIdx.x&63;
  #pragma unroll
  for (int m=0;m<10;m++){
    double t = q[m]*inv;
    Qd[(size_t)n*10+m] = (float)t;
    double p0 = (g==c0)? t:0.0;
    double p1 = (g==200)? t:0.0;
    p0=wredd(p0); p1=wredd(p1);
    if (lane==0){ part[w][m][0]=p0; part[w][m][1]=p1; }
  }
  __syncthreads();
  if (threadIdx.x < 20){
    int m = threadIdx.x>>1, cl2 = threadIdx.x&1;
    double t = part[0][m][cl2]+part[1][m][cl2]+part[2][m][cl2]+part[3][m][cl2];
    atomicAdd(&rout[m*KC + (cl2?200:c0)], (float)t);
  }
}

// fused final argmax + proto_target write + EMA accumulation (wave per pixel)
__global__ __launch_bounds__(256) void kSKEMA(const float* __restrict__ Qd, const int* __restrict__ gtseg,
      const float* __restrict__ r5, const int* __restrict__ corr, const _Float16* __restrict__ C16,
      float* __restrict__ outPT, float* __restrict__ fproto, int* __restrict__ ncnt){
  int w=threadIdx.x>>6, lane=threadIdx.x&63;
  int n = blockIdx.x*4+w;
  int g = gtseg[n];
  float tv = -1.0f;
  if (lane<10){
    float r = r5[lane*KC+g];
    float t = Qd[(size_t)n*10+lane];
    if (r>0.f) t = t/r;
    tv = t*0.1f;
  }
  float bv = tv; int bi = lane;
  #pragma unroll
  for (int o=8;o;o>>=1){
    float ov = __shfl_down(bv,o); int oi = __shfl_down(bi,o);
    if (ov>bv || (ov==bv && oi<bi)){ bv=ov; bi=oi; }
  }
  bi = __shfl(bi, 0);
  if (lane==0) outPT[n] = (float)(bi + 10*g);
  if (corr[n]){
    half8 hc = *(const half8*)(C16 + (size_t)n*DD + lane*8);
    float* dst = fproto + ((size_t)g*10+bi)*DD + lane*8;
    #pragma unroll
    for (int i=0;i<8;i++) atomicAdd(dst+i, (float)hc[i]);
    if (lane==0) atomicAdd(&ncnt[g*10+bi], 1);
  }
}

__global__ __launch_bounds__(256) void kEMAfin(const float* __restrict__ fproto, const int* __restrict__ ncnt,
     const float* __restrict__ Pn, float* __restrict__ outNP){
  int w=threadIdx.x>>6, lane=threadIdx.x&63;
  int km = blockIdx.x*4+w;
  if (km>=KM) return;
  const float* fr = fproto + (size_t)km*DD + lane*8;
  float fp[8]; float ss=0;
  #pragma unroll
  for (int i=0;i<8;i++){ fp[i]=fr[i]; ss+=fp[i]*fp[i]; }
  float n1 = fmaxf(sqrtf(__shfl(wredf(ss),0)), 1e-12f);
  int cnt = ncnt[km];
  const float* pr = Pn + (size_t)km*DD + lane*8;
  float t[8]; float s2=0;
  #pragma unroll
  for (int i=0;i<8;i++){
    float pv = pr[i];
    float tv = cnt ? (0.999f*pv + 0.001f*(fp[i]/n1)) : pv;
    t[i]=tv; s2+=tv*tv;
  }
  float n2 = fmaxf(sqrtf(__shfl(wredf(s2),0)), 1e-12f);
  float* dst = outNP + (size_t)km*DD + lane*8;
  #pragma unroll
  for (int i=0;i<8;i++) dst[i] = t[i]/n2;
}

// ================= launch =================
extern "C" void kernel_launch(void* const* d_in, const int* in_sizes, int n_in,
                              void* d_out, int out_size, void* d_ws, size_t ws_size,
                              hipStream_t stream) {
  const float* A   = (const float*)d_in[0];
  const int*   gt  = (const int*)d_in[1];
  const float* Wp  = (const float*)d_in[2];
  const float* pb  = (const float*)d_in[3];
  const float* fg  = (const float*)d_in[4];
  const float* fb  = (const float*)d_in[5];
  const float* mg  = (const float*)d_in[6];
  const float* mb  = (const float*)d_in[7];
  const float* PR  = (const float*)d_in[8];
  float* out = (float*)d_out;
  char* ws = (char*)d_ws;

  double* meanp  = (double*)(ws+OFF_MEANP);
  double* xch    = (double*)(ws+OFF_XCH);
  float*  row16  = (float*)(ws+OFF_ROW16);
  float*  row3   = (float*)(ws+OFF_ROW3);
  float*  row5   = (float*)(ws+OFF_ROW5);
  int*    Bk     = (int*)(ws+OFF_BK);
  int*    ncnt   = (int*)(ws+OFF_NCNT);
  double* mm     = (double*)(ws+OFF_MM);
  float*  fproto = (float*)(ws+OFF_FPROTO);
  int*    gtseg  = (int*)(ws+OFF_GTSEG);
  int*    corr   = (int*)(ws+OFF_CORR);
  double* u      = (double*)(ws+OFF_U);
  float*  Pn     = (float*)(ws+OFF_PN);
  _Float16* P16  = (_Float16*)(ws+OFF_P16);
  _Float16* C16  = (_Float16*)(ws+OFF_C16);
  float*  Qd     = (float*)(ws+OFF_QD);
  _Float16* W16  = (_Float16*)(ws+OFF_W16);
  _Float16* A16  = (_Float16*)(ws+OFF_A16);

  // single memset: all accumulators (mean/xchain partials, rowsums, Bk, ncnt, mm, fproto)
  hipMemsetAsync(ws, 0, ZTOTAL, stream);

  // ---- PCA pseudo-gt (un-normalized f64 power iteration; direction-equivalent) ----
  kP0<<<1024,256,0,stream>>>(A, meanp);
  for (int t=0;t<10;t++){
    const double* xp = (t==0)? nullptr : (xch + (size_t)(t-1)*8*768);
    kPIter<<<1024,256,0,stream>>>(A, meanp, xp, xch + (size_t)t*8*768);
  }
  kPU<<<1024,256,0,stream>>>(A, meanp, xch + (size_t)9*8*768, u);
  kMinMax<<<1,1024,0,stream>>>(u, mm);
  kPseudo<<<64,256,0,stream>>>(u, mm, gt, out+OUT_PG, gtseg, Bk);

  // ---- convert + normalize protos ----
  kConv<<<2048,256,0,stream>>>(A, A16, NPX*DBB/4);
  kConv<<<384,256,0,stream>>>(Wp, W16, DD*DBB/4);
  kProtoNorm<<<512,256,0,stream>>>(PR, Pn, P16);

  // ---- GEMM1: f = A @ W^T + b -> C16 (fp16), then LN+l2n ----
  gemm_f16<true><<<dim3(128,4),256,0,stream>>>(A16, W16, nullptr, C16, DBB, DD, DD, pb);
  kLNl2n<<<4096,256,0,stream>>>(C16, fg, fb);

  // ---- GEMM2: proto_logits = _c @ protos^T ----
  gemm_f16<false><<<dim3(128,16),256,0,stream>>>(C16, P16, out+OUT_PL, nullptr, DD, KM, KM, nullptr);

  // ---- fused max/LN/pred/transpose ----
  kMaxLNT<<<512,256,0,stream>>>(out+OUT_PL, mg, mb, gtseg, out+OUT_SEG, corr);

  // ---- sinkhorn (collapsed + fused) ----
  kSKcosRow<<<4096,256,0,stream>>>(C16, P16, gtseg, gt, Qd, row16);
  kSKpass<<<64,256,0,stream>>>(Qd, gtseg, gt, row16, 16, row3, Bk);
  kSKpass<<<64,256,0,stream>>>(Qd, gtseg, gt, row3, 1, row5, Bk);
  kSKEMA<<<4096,256,0,stream>>>(Qd, gtseg, row5, corr, C16, out+OUT_PT, fproto, ncnt);

  // ---- EMA finalize ----
  kEMAfin<<<503,256,0,stream>>>(fproto, ncnt, Pn, out+OUT_NP);
}